// Round 1
// baseline (1404.658 us; speedup 1.0000x reference)
//
#include <hip/hip_runtime.h>
#include <hip/hip_bf16.h>
#include <stdint.h>

#define D_DIM 1024
#define B_ROWS 65536
#define BM 128
#define BN 128
#define BK 32

typedef __bf16 bf16x8 __attribute__((ext_vector_type(8)));
typedef float f32x4 __attribute__((ext_vector_type(4)));

__device__ inline uint32_t pack_bf16(float x, float y) {
  union { float f; uint32_t u; } ax, ay;
  ax.f = x; ay.f = y;
  uint32_t ux = ax.u + 0x7FFFu + ((ax.u >> 16) & 1u);  // RNE
  uint32_t uy = ay.u + 0x7FFFu + ((ay.u >> 16) & 1u);
  return (ux >> 16) | (uy & 0xFFFF0000u);
}

__device__ inline uint16_t f32_to_bf16_rne(float x) {
  union { float f; uint32_t u; } v; v.f = x;
  uint32_t u = v.u + 0x7FFFu + ((v.u >> 16) & 1u);
  return (uint16_t)(u >> 16);
}

// ---------------------------------------------------------------------------
// Fold W = w_out @ wv  (fp32 accumulate, bf16 output), for both directions.
// M[n][k] = sum_j WO[n][j] * WV[j][k];  WV = w_in rows [2D, 3D).
// Grid: (16, 16, 2); 256 threads; 64x64 tile, 4x4 per thread, BK=16.
// ---------------------------------------------------------------------------
__global__ __launch_bounds__(256) void combine_w_kernel(
    const float* __restrict__ w_in_ab, const float* __restrict__ w_out_ab,
    const float* __restrict__ w_in_ba, const float* __restrict__ w_out_ba,
    uint16_t* __restrict__ M_ab, uint16_t* __restrict__ M_ba)
{
  const int z = blockIdx.z;
  const float* WO = z ? w_out_ba : w_out_ab;
  const float* WV = (z ? w_in_ba : w_in_ab) + 2 * D_DIM * D_DIM;
  uint16_t* M = z ? M_ba : M_ab;

  const int n0 = blockIdx.y * 64, k0 = blockIdx.x * 64;
  __shared__ float As[64][17];  // WO[n0+r][j0+c], padded
  __shared__ float Bs[16][65];  // WV[j0+r][k0+c], padded
  const int t = threadIdx.x;
  const int tx = t & 15, ty = t >> 4;

  float acc[4][4] = {};
  for (int j0 = 0; j0 < D_DIM; j0 += 16) {
    {
      int r = t >> 2, c = (t & 3) * 4;
      const float* src = WO + (uint64_t)(n0 + r) * D_DIM + j0 + c;
      As[r][c + 0] = src[0]; As[r][c + 1] = src[1];
      As[r][c + 2] = src[2]; As[r][c + 3] = src[3];
    }
    {
      int r = t >> 4, c = (t & 15) * 4;
      const float* src = WV + (uint64_t)(j0 + r) * D_DIM + k0 + c;
      Bs[r][c + 0] = src[0]; Bs[r][c + 1] = src[1];
      Bs[r][c + 2] = src[2]; Bs[r][c + 3] = src[3];
    }
    __syncthreads();
#pragma unroll
    for (int kk = 0; kk < 16; ++kk) {
      float a[4], b[4];
#pragma unroll
      for (int i = 0; i < 4; ++i) a[i] = As[ty * 4 + i][kk];
#pragma unroll
      for (int j = 0; j < 4; ++j) b[j] = Bs[kk][tx * 4 + j];
#pragma unroll
      for (int i = 0; i < 4; ++i)
#pragma unroll
        for (int j = 0; j < 4; ++j)
          acc[i][j] = fmaf(a[i], b[j], acc[i][j]);
    }
    __syncthreads();
  }
#pragma unroll
  for (int i = 0; i < 4; ++i)
#pragma unroll
    for (int j = 0; j < 4; ++j)
      M[(uint64_t)(n0 + ty * 4 + i) * D_DIM + k0 + tx * 4 + j] =
          f32_to_bf16_rne(acc[i][j]);
}

// ---------------------------------------------------------------------------
// Folded bias: bias[n] = b_out[n] + sum_j WO[n][j] * b_in[2D + j]
// Grid: (1024, 2); 256 threads; one n per block.
// ---------------------------------------------------------------------------
__global__ __launch_bounds__(256) void combine_bias_kernel(
    const float* __restrict__ w_out_ab, const float* __restrict__ b_in_ab,
    const float* __restrict__ b_out_ab,
    const float* __restrict__ w_out_ba, const float* __restrict__ b_in_ba,
    const float* __restrict__ b_out_ba,
    float* __restrict__ bias_ab, float* __restrict__ bias_ba)
{
  const int z = blockIdx.y;
  const float* WO  = z ? w_out_ba : w_out_ab;
  const float* bin = (z ? b_in_ba : b_in_ab) + 2 * D_DIM;
  const float* bo  = z ? b_out_ba : b_out_ab;
  float* bias = z ? bias_ba : bias_ab;

  const int n = blockIdx.x, t = threadIdx.x;
  float p = 0.f;
  for (int j = t; j < D_DIM; j += 256)
    p += WO[(uint64_t)n * D_DIM + j] * bin[j];
  for (int off = 32; off; off >>= 1) p += __shfl_down(p, off, 64);
  __shared__ float ws[4];
  if ((t & 63) == 0) ws[t >> 6] = p;
  __syncthreads();
  if (t == 0) bias[n] = ws[0] + ws[1] + ws[2] + ws[3] + bo[n];
}

// ---------------------------------------------------------------------------
// Main GEMM: out[:, z*D : z*D+D] = A_z @ M_zᵀ + bias_z
//   z=0: A=feat_b, M=M_ab;  z=1: A=feat_a, M=M_ba
// 128x128x32 tiles, 256 threads = 4 waves (2x2), wave does 4x4 of 16x16x32
// MFMA. A staged fp32->bf16 (RNE) in registers; B staged bf16 directly.
// ---------------------------------------------------------------------------
__global__ __launch_bounds__(256, 2) void gemm_main(
    const float* __restrict__ feat_a, const float* __restrict__ feat_b,
    const uint16_t* __restrict__ M_ab, const uint16_t* __restrict__ M_ba,
    const float* __restrict__ bias_ab, const float* __restrict__ bias_ba,
    float* __restrict__ out)
{
  const int z = blockIdx.z;
  const float* A = z ? feat_a : feat_b;
  const uint16_t* W = z ? M_ba : M_ab;
  const float* bias = z ? bias_ba : bias_ab;
  const int m0 = blockIdx.y * BM;
  const int n0 = blockIdx.x * BN;
  const int col_off = z * D_DIM;

  __shared__ __align__(16) uint16_t As[BM * BK];  // [128][32] row-major, 8 KB
  __shared__ __align__(16) uint16_t Bs[BN * BK];  // [128][32] row-major, 8 KB

  const int t = threadIdx.x;
  const int lane = t & 63, wave = t >> 6;
  const int wm = wave >> 1, wn = wave & 1;
  const int lr = lane & 15, lq = lane >> 4;

  f32x4 acc[4][4] = {};  // [mt][nt], zero-init

  // A staging: thread t -> row t/2, col base (t&1)*16 (16 fp32 = 4 float4)
  const int ar = t >> 1, ac = (t & 1) * 16;
  const float* ag = A + (uint64_t)(m0 + ar) * D_DIM + ac;
  uint4* as_dst = (uint4*)As + t * 2;  // byte offset t*32 == row-major dest

  // B staging: thread t -> row t/2, col base (t&1)*16 (16 bf16 = 2 uint4)
  const int br = t >> 1, bc = (t & 1) * 16;
  const uint16_t* bg = W + (uint64_t)(n0 + br) * D_DIM + bc;
  uint4* bs_dst = (uint4*)Bs + t * 2;

  const uint4* asv = (const uint4*)As;
  const uint4* bsv = (const uint4*)Bs;

  for (int k0 = 0; k0 < D_DIM; k0 += BK) {
    __syncthreads();
    {
      const float4* src = (const float4*)(ag + k0);
      float4 f0 = src[0], f1 = src[1], f2 = src[2], f3 = src[3];
      uint4 w0; uint4 w1;
      w0.x = pack_bf16(f0.x, f0.y); w0.y = pack_bf16(f0.z, f0.w);
      w0.z = pack_bf16(f1.x, f1.y); w0.w = pack_bf16(f1.z, f1.w);
      w1.x = pack_bf16(f2.x, f2.y); w1.y = pack_bf16(f2.z, f2.w);
      w1.z = pack_bf16(f3.x, f3.y); w1.w = pack_bf16(f3.z, f3.w);
      as_dst[0] = w0; as_dst[1] = w1;
    }
    {
      const uint4* src = (const uint4*)(bg + k0);
      uint4 b0 = src[0], b1 = src[1];
      bs_dst[0] = b0; bs_dst[1] = b1;
    }
    __syncthreads();

    bf16x8 afrag[4], bfrag[4];
#pragma unroll
    for (int mt = 0; mt < 4; ++mt)
      afrag[mt] = __builtin_bit_cast(bf16x8, asv[(wm * 64 + mt * 16 + lr) * 4 + lq]);
#pragma unroll
    for (int nt = 0; nt < 4; ++nt)
      bfrag[nt] = __builtin_bit_cast(bf16x8, bsv[(wn * 64 + nt * 16 + lr) * 4 + lq]);
#pragma unroll
    for (int mt = 0; mt < 4; ++mt)
#pragma unroll
      for (int nt = 0; nt < 4; ++nt)
        acc[mt][nt] = __builtin_amdgcn_mfma_f32_16x16x32_bf16(
            afrag[mt], bfrag[nt], acc[mt][nt], 0, 0, 0);
  }

  // Epilogue: C/D layout col=lane&15, row=(lane>>4)*4+reg (m89/m91 verified)
#pragma unroll
  for (int nt = 0; nt < 4; ++nt) {
    const int col = n0 + wn * 64 + nt * 16 + lr;
    const float bv = bias[col];
#pragma unroll
    for (int mt = 0; mt < 4; ++mt) {
      const int row = m0 + wm * 64 + mt * 16 + lq * 4;
      float* op = out + (uint64_t)row * (2 * D_DIM) + col_off + col;
#pragma unroll
      for (int r = 0; r < 4; ++r)
        op[(uint64_t)r * (2 * D_DIM)] = acc[mt][nt][r] + bv;
    }
  }
}

extern "C" void kernel_launch(void* const* d_in, const int* in_sizes, int n_in,
                              void* d_out, int out_size, void* d_ws, size_t ws_size,
                              hipStream_t stream) {
  const float* feat_a   = (const float*)d_in[0];
  const float* feat_b   = (const float*)d_in[1];
  const float* w_in_ab  = (const float*)d_in[2];
  const float* b_in_ab  = (const float*)d_in[3];
  const float* w_out_ab = (const float*)d_in[4];
  const float* b_out_ab = (const float*)d_in[5];
  const float* w_in_ba  = (const float*)d_in[6];
  const float* b_in_ba  = (const float*)d_in[7];
  const float* w_out_ba = (const float*)d_in[8];
  const float* b_out_ba = (const float*)d_in[9];
  float* out = (float*)d_out;

  uint8_t* ws = (uint8_t*)d_ws;
  uint16_t* M_ab  = (uint16_t*)(ws);                       // 2 MB
  uint16_t* M_ba  = (uint16_t*)(ws + (2u << 20));          // 2 MB
  float*    bias_ab = (float*)(ws + (4u << 20));           // 4 KB
  float*    bias_ba = (float*)(ws + (4u << 20) + 4096);    // 4 KB

  combine_w_kernel<<<dim3(16, 16, 2), 256, 0, stream>>>(
      w_in_ab, w_out_ab, w_in_ba, w_out_ba, M_ab, M_ba);
  combine_bias_kernel<<<dim3(1024, 2), 256, 0, stream>>>(
      w_out_ab, b_in_ab, b_out_ab, w_out_ba, b_in_ba, b_out_ba,
      bias_ab, bias_ba);
  gemm_main<<<dim3(D_DIM / BN, B_ROWS / BM, 2), 256, 0, stream>>>(
      feat_a, feat_b, M_ab, M_ba, bias_ab, bias_ba, out);
}

// Round 2
// 1316.678 us; speedup vs baseline: 1.0668x; 1.0668x over previous
//
#include <hip/hip_runtime.h>
#include <stdint.h>

#define D_DIM 1024
#define B_ROWS 65536

typedef __bf16 bf16x8 __attribute__((ext_vector_type(8)));
typedef float f32x4 __attribute__((ext_vector_type(4)));

typedef __attribute__((address_space(1))) uint8_t ga_u8;
typedef __attribute__((address_space(3))) uint8_t lds_u8;

// async global->LDS DMA, 16 bytes per lane. LDS dest must be
// wave-uniform-base + lane*16 contiguous (it is, by construction below).
__device__ __forceinline__ void dma16(const void* g, void* l) {
  __builtin_amdgcn_global_load_lds((ga_u8*)(uintptr_t)g,
                                   (lds_u8*)(uint32_t)(uintptr_t)l, 16, 0, 0);
}

__device__ __forceinline__ uint16_t bf16_rne(float x) {
  union { float f; uint32_t u; } v; v.f = x;
  uint32_t u = v.u + 0x7FFFu + ((v.u >> 16) & 1u);
  return (uint16_t)(u >> 16);
}
__device__ __forceinline__ float bf16_f32(uint16_t h) {
  union { uint32_t u; float f; } v; v.u = (uint32_t)h << 16;
  return v.f;
}
__device__ __forceinline__ uint32_t pk2(float x, float y) {
  return (uint32_t)bf16_rne(x) | ((uint32_t)bf16_rne(y) << 16);
}
__device__ __forceinline__ void split2(float x, uint16_t& h, uint16_t& l) {
  h = bf16_rne(x);
  l = bf16_rne(x - bf16_f32(h));
}

// ---------------------------------------------------------------------------
// fp32 -> bf16 conversion of both feature matrices.
// o0 = bf16(feat_b) (used by z=0), o1 = bf16(feat_a) (used by z=1).
// ---------------------------------------------------------------------------
__global__ __launch_bounds__(256) void conv_kernel(
    const float* __restrict__ fa, const float* __restrict__ fb,
    uint16_t* __restrict__ o0, uint16_t* __restrict__ o1)
{
  const uint32_t HALFT = 8388608u;  // (65536*1024)/8 threads per feat
  uint32_t i = blockIdx.x * 256 + threadIdx.x;
  const float* s; uint16_t* d; uint32_t t;
  if (i < HALFT) { s = fb; d = o0; t = i; }
  else           { s = fa; d = o1; t = i - HALFT; }
  uint64_t e = (uint64_t)t * 8;
  const float4* sp = (const float4*)(s + e);
  float4 f0 = sp[0], f1 = sp[1];
  uint4 w;
  w.x = pk2(f0.x, f0.y); w.y = pk2(f0.z, f0.w);
  w.z = pk2(f1.x, f1.y); w.w = pk2(f1.z, f1.w);
  *(uint4*)(d + e) = w;
}

// ---------------------------------------------------------------------------
// Weight fold via split-bf16 MFMA (fp32-equivalent accuracy, 3 MFMAs):
// M[n][k] = sum_j WO[n][j] * WV[j][k], WV = w_in rows [2D,3D). Output bf16.
// Tile 128x128, 4 waves 2x2, wave 64x64 (4x4 of 16x16x32). BJ=32.
// B operand (WV^T) is transposed into LDS during staging.
// ---------------------------------------------------------------------------
__global__ __launch_bounds__(256) void fold_w(
    const float* __restrict__ w_in_ab, const float* __restrict__ w_out_ab,
    const float* __restrict__ w_in_ba, const float* __restrict__ w_out_ba,
    uint16_t* __restrict__ M_ab, uint16_t* __restrict__ M_ba)
{
  const int z = blockIdx.z;
  const float* WO = z ? w_out_ba : w_out_ab;
  const float* WV = (z ? w_in_ba : w_in_ab) + 2 * D_DIM * D_DIM;
  uint16_t* M = z ? M_ba : M_ab;
  const int n0 = blockIdx.y * 128, k0 = blockIdx.x * 128;

  __shared__ __align__(16) uint16_t Ah[128 * 32], Al[128 * 32];
  __shared__ __align__(16) uint16_t Bh[128 * 32], Bl[128 * 32];

  const int t = threadIdx.x, lane = t & 63, w = t >> 6;
  const int wm = w >> 1, wn = w & 1;
  const int lr = lane & 15, lq = lane >> 4;

  f32x4 acc[4][4] = {};

  const int ar = t >> 1, ac = (t & 1) * 16;           // A: row ar, 16 j-cols
  const float* ag = WO + (uint64_t)(n0 + ar) * D_DIM + ac;
  const int bj = t >> 3, bc = (t & 7) * 16;           // B: j-row bj, 16 k-cols
  const float* bgp = WV + (uint64_t)bj * D_DIM + k0 + bc;

  for (int j0 = 0; j0 < D_DIM; j0 += 32) {
    __syncthreads();
    {  // stage WO tile (rows n, cols j) split into Ah/Al, row-major [128][32]
      float av[16];
      const float4* s = (const float4*)(ag + j0);
#pragma unroll
      for (int q = 0; q < 4; ++q) {
        float4 f = s[q];
        av[4*q] = f.x; av[4*q+1] = f.y; av[4*q+2] = f.z; av[4*q+3] = f.w;
      }
      uint16_t hh[16], ll[16];
#pragma unroll
      for (int i = 0; i < 16; ++i) split2(av[i], hh[i], ll[i]);
      uint4* dh = (uint4*)(Ah + t * 16);
      uint4* dl = (uint4*)(Al + t * 16);
#pragma unroll
      for (int q = 0; q < 2; ++q) {
        uint4 vh, vl;
        vh.x = (uint32_t)hh[8*q+0] | ((uint32_t)hh[8*q+1] << 16);
        vh.y = (uint32_t)hh[8*q+2] | ((uint32_t)hh[8*q+3] << 16);
        vh.z = (uint32_t)hh[8*q+4] | ((uint32_t)hh[8*q+5] << 16);
        vh.w = (uint32_t)hh[8*q+6] | ((uint32_t)hh[8*q+7] << 16);
        vl.x = (uint32_t)ll[8*q+0] | ((uint32_t)ll[8*q+1] << 16);
        vl.y = (uint32_t)ll[8*q+2] | ((uint32_t)ll[8*q+3] << 16);
        vl.z = (uint32_t)ll[8*q+4] | ((uint32_t)ll[8*q+5] << 16);
        vl.w = (uint32_t)ll[8*q+6] | ((uint32_t)ll[8*q+7] << 16);
        dh[q] = vh; dl[q] = vl;
      }
    }
    {  // stage WV tile transposed: Bh/Bl layout [k][j] (k rows of 32 j)
      const float* s = bgp + (uint64_t)j0 * D_DIM;
#pragma unroll
      for (int i = 0; i < 16; ++i) {
        float x = s[i];
        uint16_t h, l; split2(x, h, l);
        Bh[(bc + i) * 32 + bj] = h;
        Bl[(bc + i) * 32 + bj] = l;
      }
    }
    __syncthreads();

    bf16x8 ah[4], al[4], bh[4], bl[4];
    const uint4* avh = (const uint4*)Ah; const uint4* avl = (const uint4*)Al;
    const uint4* bvh = (const uint4*)Bh; const uint4* bvl = (const uint4*)Bl;
#pragma unroll
    for (int mt = 0; mt < 4; ++mt) {
      int r = (wm * 64 + mt * 16 + lr) * 4 + lq;
      ah[mt] = __builtin_bit_cast(bf16x8, avh[r]);
      al[mt] = __builtin_bit_cast(bf16x8, avl[r]);
    }
#pragma unroll
    for (int nt = 0; nt < 4; ++nt) {
      int r = (wn * 64 + nt * 16 + lr) * 4 + lq;
      bh[nt] = __builtin_bit_cast(bf16x8, bvh[r]);
      bl[nt] = __builtin_bit_cast(bf16x8, bvl[r]);
    }
#pragma unroll
    for (int mt = 0; mt < 4; ++mt)
#pragma unroll
      for (int nt = 0; nt < 4; ++nt) {
        acc[mt][nt] = __builtin_amdgcn_mfma_f32_16x16x32_bf16(ah[mt], bh[nt], acc[mt][nt], 0, 0, 0);
        acc[mt][nt] = __builtin_amdgcn_mfma_f32_16x16x32_bf16(ah[mt], bl[nt], acc[mt][nt], 0, 0, 0);
        acc[mt][nt] = __builtin_amdgcn_mfma_f32_16x16x32_bf16(al[mt], bh[nt], acc[mt][nt], 0, 0, 0);
      }
  }

#pragma unroll
  for (int nt = 0; nt < 4; ++nt) {
    const int col = k0 + wn * 64 + nt * 16 + lr;
#pragma unroll
    for (int mt = 0; mt < 4; ++mt) {
      const int rowb = n0 + wm * 64 + mt * 16 + lq * 4;
#pragma unroll
      for (int r = 0; r < 4; ++r)
        M[(uint64_t)(rowb + r) * D_DIM + col] = bf16_rne(acc[mt][nt][r]);
    }
  }
}

// ---------------------------------------------------------------------------
// Folded bias: bias[n] = b_out[n] + sum_j WO[n][j] * b_in[2D + j]
// ---------------------------------------------------------------------------
__global__ __launch_bounds__(256) void fold_bias(
    const float* __restrict__ w_out_ab, const float* __restrict__ b_in_ab,
    const float* __restrict__ b_out_ab,
    const float* __restrict__ w_out_ba, const float* __restrict__ b_in_ba,
    const float* __restrict__ b_out_ba,
    float* __restrict__ bias_ab, float* __restrict__ bias_ba)
{
  const int z = blockIdx.y;
  const float* WO  = z ? w_out_ba : w_out_ab;
  const float* bin = (z ? b_in_ba : b_in_ab) + 2 * D_DIM;
  const float* bo  = z ? b_out_ba : b_out_ab;
  float* bias = z ? bias_ba : bias_ab;

  const int n = blockIdx.x, t = threadIdx.x;
  float p = 0.f;
  for (int j = t; j < D_DIM; j += 256)
    p += WO[(uint64_t)n * D_DIM + j] * bin[j];
  for (int off = 32; off; off >>= 1) p += __shfl_down(p, off, 64);
  __shared__ float ws[4];
  if ((t & 63) == 0) ws[t >> 6] = p;
  __syncthreads();
  if (t == 0) bias[n] = ws[0] + ws[1] + ws[2] + ws[3] + bo[n];
}

// ---------------------------------------------------------------------------
// Main GEMM: out[:, z*D : z*D+D] = A_z @ M_z^T + bias_z
// BM=256, BN=128, BK=32. 4 waves (2x2), wave tile 128x64 (8x4 of 16x16x32).
// XCD swizzle: 1D grid, lin -> (xcd=lin&7, ntile=(lin>>3)&7, group=lin>>6);
// panel mp = group*8+xcd. The 8 n-tiles of one A-panel occupy 8 consecutive
// slots on ONE XCD -> A panel fetched from HBM once, 7 L2 hits.
// PRECONV=true: A is pre-converted bf16, staged via global_load_lds (as is B).
// PRECONV=false (ws fallback): A fp32, register-converted to bf16.
// ---------------------------------------------------------------------------
template <bool PRECONV>
__global__ __launch_bounds__(256, 2) void gemm_main(
    const void* __restrict__ A0, const void* __restrict__ A1,
    const uint16_t* __restrict__ M_ab, const uint16_t* __restrict__ M_ba,
    const float* __restrict__ bias_ab, const float* __restrict__ bias_ba,
    float* __restrict__ out)
{
  const uint32_t lin = blockIdx.x;
  const uint32_t xcd = lin & 7, j = (lin >> 3) & 7, g = lin >> 6;
  const uint32_t mp = g * 8 + xcd;          // 0..511
  const uint32_t z  = mp >> 8;
  const uint32_t m0 = (mp & 255) * 256;
  const uint32_t n0 = j * 128;

  const void* Aany = z ? A1 : A0;
  const uint16_t* W = z ? M_ba : M_ab;
  const float* bias = z ? bias_ba : bias_ab;

  __shared__ __align__(16) uint16_t As[256 * 32];  // 16 KB
  __shared__ __align__(16) uint16_t Bs[128 * 32];  //  8 KB

  const int t = threadIdx.x, lane = t & 63, w = t >> 6;
  const int wm = w >> 1, wn = w & 1;
  const int lr = lane & 15, lq = lane >> 4;

  f32x4 acc[8][4] = {};

  // DMA staging maps (row-major [rows][32] bf16, 64 B per row):
  const int qrow = lane >> 2;           // 0..15
  const int qcol = (lane & 3) * 8;      // element col base
  const uint16_t* abf = (const uint16_t*)Aany;
  const uint16_t* ag  = abf + (uint64_t)(m0 + w * 64 + qrow) * D_DIM + qcol;
  uint16_t* al0 = As + w * 2048 + lane * 8;   // + q*512 per issue
  const uint16_t* bg = W + (uint64_t)(n0 + w * 32 + qrow) * D_DIM + qcol;
  uint16_t* bl0 = Bs + w * 1024 + lane * 8;   // + q*512 per issue

  // fused-path map: thread t stages row t (32 fp32 -> 32 bf16)
  const float* afp = (const float*)Aany + (uint64_t)(m0 + t) * D_DIM;

  for (int k0 = 0; k0 < D_DIM; k0 += 32) {
    __syncthreads();
    if constexpr (PRECONV) {
#pragma unroll
      for (int q = 0; q < 4; ++q)
        dma16(ag + k0 + q * 16 * D_DIM, al0 + q * 512);
    } else {
      const float4* src = (const float4*)(afp + k0);
      float4 f[8];
#pragma unroll
      for (int q = 0; q < 8; ++q) f[q] = src[q];
      uint4* dst = (uint4*)(As + t * 32);
#pragma unroll
      for (int q = 0; q < 4; ++q) {
        uint4 wv;
        wv.x = pk2(f[2*q].x,   f[2*q].y);   wv.y = pk2(f[2*q].z,   f[2*q].w);
        wv.z = pk2(f[2*q+1].x, f[2*q+1].y); wv.w = pk2(f[2*q+1].z, f[2*q+1].w);
        dst[q] = wv;
      }
    }
#pragma unroll
    for (int q = 0; q < 2; ++q)
      dma16(bg + k0 + q * 16 * D_DIM, bl0 + q * 512);
    __syncthreads();

    bf16x8 a[8], b[4];
    const uint4* asv = (const uint4*)As;
    const uint4* bsv = (const uint4*)Bs;
#pragma unroll
    for (int mt = 0; mt < 8; ++mt)
      a[mt] = __builtin_bit_cast(bf16x8, asv[(wm * 128 + mt * 16 + lr) * 4 + lq]);
#pragma unroll
    for (int nt = 0; nt < 4; ++nt)
      b[nt] = __builtin_bit_cast(bf16x8, bsv[(wn * 64 + nt * 16 + lr) * 4 + lq]);
#pragma unroll
    for (int mt = 0; mt < 8; ++mt)
#pragma unroll
      for (int nt = 0; nt < 4; ++nt)
        acc[mt][nt] = __builtin_amdgcn_mfma_f32_16x16x32_bf16(a[mt], b[nt], acc[mt][nt], 0, 0, 0);
  }

  // Epilogue: C/D layout col=lane&15, row=(lane>>4)*4+reg
  const uint32_t col_off = z * D_DIM;
#pragma unroll
  for (int nt = 0; nt < 4; ++nt) {
    const int col = n0 + wn * 64 + nt * 16 + lr;
    const float bv = bias[col];
#pragma unroll
    for (int mt = 0; mt < 8; ++mt) {
      const int row = m0 + wm * 128 + mt * 16 + lq * 4;
      float* op = out + (uint64_t)row * (2 * D_DIM) + col_off + col;
#pragma unroll
      for (int r = 0; r < 4; ++r)
        op[(uint64_t)r * (2 * D_DIM)] = acc[mt][nt][r] + bv;
    }
  }
}

extern "C" void kernel_launch(void* const* d_in, const int* in_sizes, int n_in,
                              void* d_out, int out_size, void* d_ws, size_t ws_size,
                              hipStream_t stream) {
  const float* feat_a   = (const float*)d_in[0];
  const float* feat_b   = (const float*)d_in[1];
  const float* w_in_ab  = (const float*)d_in[2];
  const float* b_in_ab  = (const float*)d_in[3];
  const float* w_out_ab = (const float*)d_in[4];
  const float* b_out_ab = (const float*)d_in[5];
  const float* w_in_ba  = (const float*)d_in[6];
  const float* b_in_ba  = (const float*)d_in[7];
  const float* w_out_ba = (const float*)d_in[8];
  const float* b_out_ba = (const float*)d_in[9];
  float* out = (float*)d_out;

  uint8_t* ws = (uint8_t*)d_ws;
  const size_t FEAT_B2 = (size_t)B_ROWS * D_DIM * 2;           // 128 MB
  const size_t need = 2 * FEAT_B2 + (4u << 20) + 8192;
  const bool big = ws_size >= need;

  uint16_t *A0 = nullptr, *A1 = nullptr, *M_ab, *M_ba;
  float *bias_ab, *bias_ba;
  if (big) {
    A0 = (uint16_t*)ws;
    A1 = (uint16_t*)(ws + FEAT_B2);
    M_ab = (uint16_t*)(ws + 2 * FEAT_B2);
    M_ba = (uint16_t*)(ws + 2 * FEAT_B2 + (2u << 20));
    bias_ab = (float*)(ws + 2 * FEAT_B2 + (4u << 20));
    bias_ba = (float*)(ws + 2 * FEAT_B2 + (4u << 20) + 4096);
  } else {
    M_ab = (uint16_t*)ws;
    M_ba = (uint16_t*)(ws + (2u << 20));
    bias_ab = (float*)(ws + (4u << 20));
    bias_ba = (float*)(ws + (4u << 20) + 4096);
  }

  fold_w<<<dim3(8, 8, 2), 256, 0, stream>>>(
      w_in_ab, w_out_ab, w_in_ba, w_out_ba, M_ab, M_ba);
  fold_bias<<<dim3(1024, 2), 256, 0, stream>>>(
      w_out_ab, b_in_ab, b_out_ab, w_out_ba, b_in_ba, b_out_ba,
      bias_ab, bias_ba);

  if (big) {
    conv_kernel<<<65536, 256, 0, stream>>>(feat_a, feat_b, A0, A1);
    gemm_main<true><<<4096, 256, 0, stream>>>(
        A0, A1, M_ab, M_ba, bias_ab, bias_ba, out);
  } else {
    gemm_main<false><<<4096, 256, 0, stream>>>(
        feat_b, feat_a, M_ab, M_ba, bias_ab, bias_ba, out);
  }
}